// Round 11
// baseline (143.550 us; speedup 1.0000x reference)
//
#include <hip/hip_runtime.h>

typedef short s16x8 __attribute__((ext_vector_type(8)));
typedef float f32x4 __attribute__((ext_vector_type(4)));
typedef unsigned short u16;

#define BN_EPS 1e-5f

__device__ __forceinline__ u16 f2bf(float f) {
  union { float f; unsigned u; } v; v.f = f;
  unsigned r = (v.u + 0x7fffu + ((v.u >> 16) & 1u)) >> 16;
  return (u16)r;
}

// -------- setup helper: pack per-lane B fragments + BN (inv, shift) --------
__device__ void setup_one(
    const float* __restrict__ w, const float* __restrict__ bias,
    const float* __restrict__ g, const float* __restrict__ be,
    const float* __restrict__ mu, const float* __restrict__ var,
    u16* __restrict__ Bp, float* __restrict__ bnp,
    int CIN, int CIP, int KSTEPS, int e)
{
  if (e < 48) {
    float iv = g[e] * rsqrtf(var[e] + BN_EPS);
    bnp[e] = iv;
    bnp[48 + e] = (bias[e] - mu[e]) * iv + be[e];
  }
  int total = 4 * KSTEPS * 1536;
  if (e >= total) return;
  int j = e & 7;
  int l = (e >> 3) & 63;
  int nt = (e >> 9) % 3;
  int sp = e / 1536;
  int s = sp % KSTEPS;
  int p = sp / KSTEPS;
  int py = p >> 1, px = p & 1;
  int n = nt * 16 + (l & 15);
  int k = s * 32 + (l >> 4) * 8 + j;
  int tap = k / CIP, ci = k % CIP;
  int kh = 2 * (tap >> 1) + 1 - py;
  int kw = 2 * (tap & 1) + 1 - px;
  float v = (ci < CIN) ? w[((ci * 48 + n) * 4 + kh) * 4 + kw] : 0.f;
  Bp[e] = f2bf(v);
}

// -------- fused prep: DWT l1+l2 (blocks 0..767) + weight packing (768+) ----
__global__ __launch_bounds__(256) void prep_kernel(
    const float* __restrict__ x, u16* __restrict__ xl1, u16* __restrict__ xl2,
    const float* w1, const float* b1, const float* g1, const float* be1,
    const float* m1, const float* v1, u16* Bp1, float* bnp1,
    const float* w2a, const float* b2a, const float* g2a, const float* be2a,
    const float* m2a, const float* v2a, u16* Bp2a, float* bnp2a,
    const float* w2b, const float* b2b, const float* g2b, const float* be2b,
    const float* m2b, const float* v2b, u16* Bp2b, float* bnp2b)
{
  if (blockIdx.x >= 768) {
    int sub = blockIdx.x - 768;           // 432 blocks: 144 per conv
    int which = sub / 144;
    int e = (sub % 144) * 256 + threadIdx.x;
    if (which == 0)      setup_one(w1, b1, g1, be1, m1, v1, Bp1, bnp1, 12, 16, 2, e);
    else if (which == 1) setup_one(w2a, b2a, g2a, be2a, m2a, v2a, Bp2a, bnp2a, 48, 48, 6, e);
    else                 setup_one(w2b, b2b, g2b, be2b, m2b, v2b, Bp2b, bnp2b, 48, 48, 6, e);
    return;
  }
  int idx = blockIdx.x * 256 + threadIdx.x;   // 16*3*64*64 = 196608
  int w4 = idx & 63; int t = idx >> 6;
  int h4 = t & 63; t >>= 6;
  int c = t % 3; int b = t / 3;
  const float* p = x + (((long)(b * 3 + c) * 256 + 4 * h4) * 256 + 4 * w4);
  float4 r0 = *(const float4*)p;
  float4 r1 = *(const float4*)(p + 256);
  float4 r2 = *(const float4*)(p + 512);
  float4 r3 = *(const float4*)(p + 768);
  float rows[4][4] = {{r0.x, r0.y, r0.z, r0.w}, {r1.x, r1.y, r1.z, r1.w},
                      {r2.x, r2.y, r2.z, r2.w}, {r3.x, r3.y, r3.z, r3.w}};
  float sb[4][2][2];
  #pragma unroll
  for (int qy = 0; qy < 2; ++qy)
    #pragma unroll
    for (int qx = 0; qx < 2; ++qx) {
      float a = rows[2 * qy][2 * qx],      bb = rows[2 * qy][2 * qx + 1];
      float cc = rows[2 * qy + 1][2 * qx], dd = rows[2 * qy + 1][2 * qx + 1];
      sb[0][qy][qx] = (a + bb + cc + dd) * 0.5f;
      sb[1][qy][qx] = (a + bb - cc - dd) * 0.5f;
      sb[2][qy][qx] = (a - bb + cc - dd) * 0.5f;
      sb[3][qy][qx] = (a - bb - cc + dd) * 0.5f;
    }
  #pragma unroll
  for (int s = 0; s < 4; ++s)
    #pragma unroll
    for (int qy = 0; qy < 2; ++qy) {
      unsigned pk = (unsigned)f2bf(sb[s][qy][0]) | ((unsigned)f2bf(sb[s][qy][1]) << 16);
      *(unsigned*)&xl1[(((long)(b * 12 + 4 * c + s) * 128) + 2 * h4 + qy) * 128 + 2 * w4] = pk;
    }
  #pragma unroll
  for (int s = 0; s < 4; ++s) {
    float a = sb[s][0][0], bb = sb[s][0][1], cc = sb[s][1][0], dd = sb[s][1][1];
    float o[4] = {(a + bb + cc + dd) * 0.5f, (a + bb - cc - dd) * 0.5f,
                  (a - bb + cc - dd) * 0.5f, (a - bb - cc + dd) * 0.5f};
    #pragma unroll
    for (int s2 = 0; s2 < 4; ++s2)
      xl2[(((long)(b * 48 + (4 * c + s) * 4 + s2) * 64) + h4) * 64 + w4] = f2bf(o[s2]);
  }
}

// -------- ConvT(4,2,1)+BN+ReLU via MFMA implicit GEMM (32-wide tile) -------
// Block: 32x4 input quads (64x8 output) x all 48 co. 4 waves = 4 parities.
// LDS 27.8KB (CIP=48), BN loads in epilogue -> target 5 blocks/CU.
template<int CIN, int CIP, int HIN, int WIN, bool OBF16>
__global__ __launch_bounds__(256, 5) void convt_mfma(
    const u16* __restrict__ in,    // (B, CIN, HIN, WIN) bf16
    const u16* __restrict__ Bp,    // packed B fragments
    const float* __restrict__ bnp, // inv[48], sh[48]
    void* __restrict__ outv, int outc, int obase)
{
  constexpr int KSTEPS = CIP / 8;
  constexpr int ITX = 34, ITY = 6;
  constexpr int HOUT = 2 * HIN, WOUT = 2 * WIN;
  __shared__ __align__(16) u16 in_lds[ITX * ITY * CIP];
  __shared__ __align__(16) float out_lds[16 * 2 * 64];   // 8 KB

  const int tid = threadIdx.x;
  const int n = blockIdx.z;
  const int qY0 = blockIdx.y * 4;
  const int qX0 = blockIdx.x * 32;

  // ---- stage input tile [y][x][ci_rot], 16B loads + halo ----
  {
    constexpr int NTASK = CIP * ITY * 4;
    for (int t = tid; t < NTASK; t += 256) {
      int seg = t & 3;
      int rowid = t >> 2;
      int ci = rowid / ITY;
      int y = rowid - ci * ITY;
      int ih = qY0 - 1 + y;
      bool rowok = (CIP == CIN || ci < CIN) && ((unsigned)ih < (unsigned)HIN);
      const u16* gsrc = in + (((long)n * CIN + ci) * HIN + ih) * WIN + qX0 + 8 * seg;
      s16x8 v = {0, 0, 0, 0, 0, 0, 0, 0};
      if (rowok) v = *(const s16x8*)gsrc;
      int base_yx = y * ITX;
      #pragma unroll
      for (int j = 0; j < 8; ++j) {
        int xx = 1 + 8 * seg + j;
        int rot = 8 * ((xx >> 2) & 3);
        if (rot >= CIP) rot -= CIP;
        int cr = ci + rot;
        if (cr >= CIP) cr -= CIP;
        in_lds[(base_yx + xx) * CIP + cr] = (u16)v[j];
      }
      if (seg == 0 || seg == 3) {
        int xh = (seg == 0) ? 0 : 33;
        int iwh = qX0 - 1 + xh;
        u16 hv = 0;
        if (rowok && (unsigned)iwh < (unsigned)WIN) hv = gsrc[(seg == 0) ? -1 : 8];
        int rot = 8 * ((xh >> 2) & 3);
        if (rot >= CIP) rot -= CIP;
        int cr = ci + rot;
        if (cr >= CIP) cr -= CIP;
        in_lds[(base_yx + xh) * CIP + cr] = hv;
      }
    }
  }

  const int wid = tid >> 6, lane = tid & 63;
  const int py = wid >> 1, px = wid & 1;
  const int g = lane >> 4, qx = lane & 15;

  const s16x8* bpp = (const s16x8*)Bp + (wid * KSTEPS * 3) * 64 + lane;

  int abase[KSTEPS];
  #pragma unroll
  for (int s = 0; s < KSTEPS; ++s) {
    int k0 = s * 32 + g * 8;
    int tap = k0 / CIP, ci0 = k0 - tap * CIP;
    int ty = tap >> 1, tx = tap & 1;
    int y = 1 + py - ty;
    int xx = qx + 1 + px - tx;
    int rot = 8 * ((xx >> 2) & 3);
    if (rot >= CIP) rot -= CIP;
    int cr = ci0 + rot;
    if (cr >= CIP) cr -= CIP;
    abase[s] = (y * ITX + xx) * CIP + cr;
  }

  __syncthreads();

  for (int mc = 0; mc < 4; ++mc) {
    f32x4 acc[2][3];
    #pragma unroll
    for (int mt = 0; mt < 2; ++mt)
      #pragma unroll
      for (int nt = 0; nt < 3; ++nt)
        acc[mt][nt] = f32x4{0.f, 0.f, 0.f, 0.f};

    #pragma unroll
    for (int s = 0; s < KSTEPS; ++s) {
      s16x8 bf0 = bpp[(s * 3 + 0) * 64];
      s16x8 bf1 = bpp[(s * 3 + 1) * 64];
      s16x8 bf2 = bpp[(s * 3 + 2) * 64];
      #pragma unroll
      for (int mt = 0; mt < 2; ++mt) {
        s16x8 a = *(const s16x8*)&in_lds[abase[s] + (mc * ITX + mt * 16) * CIP];
        acc[mt][0] = __builtin_amdgcn_mfma_f32_16x16x32_bf16(bf0, a, acc[mt][0], 0, 0, 0);
        acc[mt][1] = __builtin_amdgcn_mfma_f32_16x16x32_bf16(bf1, a, acc[mt][1], 0, 0, 0);
        acc[mt][2] = __builtin_amdgcn_mfma_f32_16x16x32_bf16(bf2, a, acc[mt][2], 0, 0, 0);
      }
    }

    // ---- epilogue: 3 chunks of 16 co; BN loaded per chunk ----
    #pragma unroll
    for (int nt = 0; nt < 3; ++nt) {
      __syncthreads();   // out_lds free
      float4 iv4 = *(const float4*)&bnp[nt * 16 + 4 * g];
      float4 sv4 = *(const float4*)&bnp[48 + nt * 16 + 4 * g];
      #pragma unroll
      for (int mt = 0; mt < 2; ++mt) {
        #pragma unroll
        for (int r = 0; r < 4; ++r) {
          const int co_rel = 4 * g + r;
          float iv = ((const float*)&iv4)[r];
          float sv = ((const float*)&sv4)[r];
          float val = fmaxf(acc[mt][nt][r] * iv + sv, 0.f);
          out_lds[(co_rel * 2 + py) * 64 + 2 * (mt * 16 + qx) + px] = val;
        }
      }
      __syncthreads();   // out_lds filled
      // 16 co * 2 parities * 16 float4 = 512 float4 -> 2 iters
      #pragma unroll
      for (int u = 0; u < 2; ++u) {
        int e = u * 256 + tid;
        int ow4 = e & 15, row = e >> 4;
        int co_l = nt * 16 + (row >> 1), ohp = row & 1;
        f32x4 vv = *(const f32x4*)&out_lds[row * 64 + 4 * ow4];
        long off = (((long)(n * outc + obase + co_l) * HOUT + 2 * (qY0 + mc) + ohp) * WOUT)
                   + 2 * qX0 + 4 * ow4;
        if (OBF16) {
          unsigned lo = (unsigned)f2bf(vv.x) | ((unsigned)f2bf(vv.y) << 16);
          unsigned hi = (unsigned)f2bf(vv.z) | ((unsigned)f2bf(vv.w) << 16);
          uint2 pk; pk.x = lo; pk.y = hi;
          *(uint2*)((u16*)outv + off) = pk;
        } else {
          __builtin_nontemporal_store(vv, (f32x4*)((float*)outv + off));
        }
      }
    }
  }
}

extern "C" void kernel_launch(void* const* d_in, const int* in_sizes, int n_in,
                              void* d_out, int out_size, void* d_ws, size_t ws_size,
                              hipStream_t stream) {
  const float* x    = (const float*)d_in[0];
  const float* w1   = (const float*)d_in[1];
  const float* b1   = (const float*)d_in[2];
  const float* g1   = (const float*)d_in[3];
  const float* be1  = (const float*)d_in[4];
  const float* m1   = (const float*)d_in[5];
  const float* v1   = (const float*)d_in[6];
  const float* w2a  = (const float*)d_in[7];
  const float* b2a  = (const float*)d_in[8];
  const float* g2a  = (const float*)d_in[9];
  const float* be2a = (const float*)d_in[10];
  const float* m2a  = (const float*)d_in[11];
  const float* v2a  = (const float*)d_in[12];
  const float* w2b  = (const float*)d_in[13];
  const float* b2b  = (const float*)d_in[14];
  const float* g2b  = (const float*)d_in[15];
  const float* be2b = (const float*)d_in[16];
  const float* m2b  = (const float*)d_in[17];
  const float* v2b  = (const float*)d_in[18];

  float* out = (float*)d_out;
  char* ws = (char*)d_ws;
  u16* xl1  = (u16*)ws;                         // 6291456 B
  u16* xl2  = (u16*)(ws + 6291456);             // 6291456 B
  u16* o2a  = (u16*)(ws + 12582912);            // 25165824 B
  u16* Bp1  = (u16*)(ws + 37748736);
  u16* Bp2a = (u16*)(ws + 37773312);
  u16* Bp2b = (u16*)(ws + 37847040);
  float* bnp1  = (float*)(ws + 37920768);
  float* bnp2a = (float*)(ws + 37921152);
  float* bnp2b = (float*)(ws + 37921536);

  // fused: dwt l1+l2 (768 blocks) + 3x setup (432 blocks)
  prep_kernel<<<1200, 256, 0, stream>>>(
      x, xl1, xl2,
      w1, b1, g1, be1, m1, v1, Bp1, bnp1,
      w2a, b2a, g2a, be2a, m2a, v2a, Bp2a, bnp2a,
      w2b, b2b, g2b, be2b, m2b, v2b, Bp2b, bnp2b);

  // conv2a: (16,48,64,64) -> o2a (bf16)
  convt_mfma<48, 48, 64, 64, true><<<dim3(2, 16, 16), 256, 0, stream>>>(
      xl2, Bp2a, bnp2a, o2a, 48, 0);
  // conv1: (16,12,128,128) -> out ch 0..47 (fp32)
  convt_mfma<12, 16, 128, 128, false><<<dim3(4, 32, 16), 256, 0, stream>>>(
      xl1, Bp1, bnp1, out, 96, 0);
  // conv2b: (16,48,128,128) -> out ch 48..95 (fp32)
  convt_mfma<48, 48, 128, 128, false><<<dim3(4, 32, 16), 256, 0, stream>>>(
      o2a, Bp2b, bnp2b, out, 96, 48);
}

// Round 12
// 117.872 us; speedup vs baseline: 1.2179x; 1.2179x over previous
//
#include <hip/hip_runtime.h>

typedef short s16x8 __attribute__((ext_vector_type(8)));
typedef float f32x4 __attribute__((ext_vector_type(4)));
typedef unsigned short u16;

#define BN_EPS 1e-5f

__device__ __forceinline__ u16 f2bf(float f) {
  union { float f; unsigned u; } v; v.f = f;
  unsigned r = (v.u + 0x7fffu + ((v.u >> 16) & 1u)) >> 16;
  return (u16)r;
}

// -------- setup helper: pack per-lane B fragments + BN (inv, shift) --------
__device__ void setup_one(
    const float* __restrict__ w, const float* __restrict__ bias,
    const float* __restrict__ g, const float* __restrict__ be,
    const float* __restrict__ mu, const float* __restrict__ var,
    u16* __restrict__ Bp, float* __restrict__ bnp,
    int CIN, int CIP, int KSTEPS, int e)
{
  if (e < 48) {
    float iv = g[e] * rsqrtf(var[e] + BN_EPS);
    bnp[e] = iv;
    bnp[48 + e] = (bias[e] - mu[e]) * iv + be[e];
  }
  int total = 4 * KSTEPS * 1536;
  if (e >= total) return;
  int j = e & 7;
  int l = (e >> 3) & 63;
  int nt = (e >> 9) % 3;
  int sp = e / 1536;
  int s = sp % KSTEPS;
  int p = sp / KSTEPS;
  int py = p >> 1, px = p & 1;
  int n = nt * 16 + (l & 15);
  int k = s * 32 + (l >> 4) * 8 + j;
  int tap = k / CIP, ci = k % CIP;
  int kh = 2 * (tap >> 1) + 1 - py;
  int kw = 2 * (tap & 1) + 1 - px;
  float v = (ci < CIN) ? w[((ci * 48 + n) * 4 + kh) * 4 + kw] : 0.f;
  Bp[e] = f2bf(v);
}

// -------- fused prep: DWT l1+l2 (blocks 0..767) + weight packing (768+) ----
__global__ __launch_bounds__(256) void prep_kernel(
    const float* __restrict__ x, u16* __restrict__ xl1, u16* __restrict__ xl2,
    const float* w1, const float* b1, const float* g1, const float* be1,
    const float* m1, const float* v1, u16* Bp1, float* bnp1,
    const float* w2a, const float* b2a, const float* g2a, const float* be2a,
    const float* m2a, const float* v2a, u16* Bp2a, float* bnp2a,
    const float* w2b, const float* b2b, const float* g2b, const float* be2b,
    const float* m2b, const float* v2b, u16* Bp2b, float* bnp2b)
{
  if (blockIdx.x >= 768) {
    int sub = blockIdx.x - 768;           // 432 blocks: 144 per conv
    int which = sub / 144;
    int e = (sub % 144) * 256 + threadIdx.x;
    if (which == 0)      setup_one(w1, b1, g1, be1, m1, v1, Bp1, bnp1, 12, 16, 2, e);
    else if (which == 1) setup_one(w2a, b2a, g2a, be2a, m2a, v2a, Bp2a, bnp2a, 48, 48, 6, e);
    else                 setup_one(w2b, b2b, g2b, be2b, m2b, v2b, Bp2b, bnp2b, 48, 48, 6, e);
    return;
  }
  int idx = blockIdx.x * 256 + threadIdx.x;   // 16*3*64*64 = 196608
  int w4 = idx & 63; int t = idx >> 6;
  int h4 = t & 63; t >>= 6;
  int c = t % 3; int b = t / 3;
  const float* p = x + (((long)(b * 3 + c) * 256 + 4 * h4) * 256 + 4 * w4);
  float4 r0 = *(const float4*)p;
  float4 r1 = *(const float4*)(p + 256);
  float4 r2 = *(const float4*)(p + 512);
  float4 r3 = *(const float4*)(p + 768);
  float rows[4][4] = {{r0.x, r0.y, r0.z, r0.w}, {r1.x, r1.y, r1.z, r1.w},
                      {r2.x, r2.y, r2.z, r2.w}, {r3.x, r3.y, r3.z, r3.w}};
  float sb[4][2][2];
  #pragma unroll
  for (int qy = 0; qy < 2; ++qy)
    #pragma unroll
    for (int qx = 0; qx < 2; ++qx) {
      float a = rows[2 * qy][2 * qx],      bb = rows[2 * qy][2 * qx + 1];
      float cc = rows[2 * qy + 1][2 * qx], dd = rows[2 * qy + 1][2 * qx + 1];
      sb[0][qy][qx] = (a + bb + cc + dd) * 0.5f;
      sb[1][qy][qx] = (a + bb - cc - dd) * 0.5f;
      sb[2][qy][qx] = (a - bb + cc - dd) * 0.5f;
      sb[3][qy][qx] = (a - bb - cc + dd) * 0.5f;
    }
  #pragma unroll
  for (int s = 0; s < 4; ++s)
    #pragma unroll
    for (int qy = 0; qy < 2; ++qy) {
      unsigned pk = (unsigned)f2bf(sb[s][qy][0]) | ((unsigned)f2bf(sb[s][qy][1]) << 16);
      *(unsigned*)&xl1[(((long)(b * 12 + 4 * c + s) * 128) + 2 * h4 + qy) * 128 + 2 * w4] = pk;
    }
  #pragma unroll
  for (int s = 0; s < 4; ++s) {
    float a = sb[s][0][0], bb = sb[s][0][1], cc = sb[s][1][0], dd = sb[s][1][1];
    float o[4] = {(a + bb + cc + dd) * 0.5f, (a + bb - cc - dd) * 0.5f,
                  (a - bb + cc - dd) * 0.5f, (a - bb - cc + dd) * 0.5f};
    #pragma unroll
    for (int s2 = 0; s2 < 4; ++s2)
      xl2[(((long)(b * 48 + (4 * c + s) * 4 + s2) * 64) + h4) * 64 + w4] = f2bf(o[s2]);
  }
}

// -------- ConvT(4,2,1)+BN+ReLU via MFMA implicit GEMM (32-wide tile) -------
// Block: 32x4 input quads (64x8 output) x all 48 co. 4 waves = 4 parities.
// BIGEPI: single 48-co epilogue chunk (24KB out_lds, half the barriers) —
//         used for conv1 (CIP=16, in_lds only 6.4KB).
template<int CIN, int CIP, int HIN, int WIN, bool OBF16, bool BIGEPI>
__global__ __launch_bounds__(256, 4) void convt_mfma(
    const u16* __restrict__ in,    // (B, CIN, HIN, WIN) bf16
    const u16* __restrict__ Bp,    // packed B fragments
    const float* __restrict__ bnp, // inv[48], sh[48]
    void* __restrict__ outv, int outc, int obase)
{
  constexpr int KSTEPS = CIP / 8;
  constexpr int ITX = 34, ITY = 6;
  constexpr int HOUT = 2 * HIN, WOUT = 2 * WIN;
  __shared__ __align__(16) u16 in_lds[ITX * ITY * CIP];
  __shared__ __align__(16) float out_lds[(BIGEPI ? 48 : 32) * 2 * 64];

  const int tid = threadIdx.x;
  const int n = blockIdx.z;
  const int qY0 = blockIdx.y * 4;
  const int qX0 = blockIdx.x * 32;

  // ---- stage input tile [y][x][ci_rot], 16B loads + halo ----
  {
    constexpr int NTASK = CIP * ITY * 4;
    for (int t = tid; t < NTASK; t += 256) {
      int seg = t & 3;
      int rowid = t >> 2;
      int ci = rowid / ITY;
      int y = rowid - ci * ITY;
      int ih = qY0 - 1 + y;
      bool rowok = (CIP == CIN || ci < CIN) && ((unsigned)ih < (unsigned)HIN);
      const u16* gsrc = in + (((long)n * CIN + ci) * HIN + ih) * WIN + qX0 + 8 * seg;
      s16x8 v = {0, 0, 0, 0, 0, 0, 0, 0};
      if (rowok) v = *(const s16x8*)gsrc;
      int base_yx = y * ITX;
      #pragma unroll
      for (int j = 0; j < 8; ++j) {
        int xx = 1 + 8 * seg + j;
        int rot = 8 * ((xx >> 2) & 3);
        if (rot >= CIP) rot -= CIP;
        int cr = ci + rot;
        if (cr >= CIP) cr -= CIP;
        in_lds[(base_yx + xx) * CIP + cr] = (u16)v[j];
      }
      if (seg == 0 || seg == 3) {
        int xh = (seg == 0) ? 0 : 33;
        int iwh = qX0 - 1 + xh;
        u16 hv = 0;
        if (rowok && (unsigned)iwh < (unsigned)WIN) hv = gsrc[(seg == 0) ? -1 : 8];
        int rot = 8 * ((xh >> 2) & 3);
        if (rot >= CIP) rot -= CIP;
        int cr = ci + rot;
        if (cr >= CIP) cr -= CIP;
        in_lds[(base_yx + xh) * CIP + cr] = hv;
      }
    }
  }

  const int wid = tid >> 6, lane = tid & 63;
  const int py = wid >> 1, px = wid & 1;
  const int g = lane >> 4, qx = lane & 15;

  const s16x8* bpp = (const s16x8*)Bp + (wid * KSTEPS * 3) * 64 + lane;

  float4 inv4[3], sh4[3];
  #pragma unroll
  for (int nt = 0; nt < 3; ++nt) {
    inv4[nt] = *(const float4*)&bnp[nt * 16 + 4 * g];
    sh4[nt]  = *(const float4*)&bnp[48 + nt * 16 + 4 * g];
  }

  int abase[KSTEPS];
  #pragma unroll
  for (int s = 0; s < KSTEPS; ++s) {
    int k0 = s * 32 + g * 8;
    int tap = k0 / CIP, ci0 = k0 - tap * CIP;
    int ty = tap >> 1, tx = tap & 1;
    int y = 1 + py - ty;
    int xx = qx + 1 + px - tx;
    int rot = 8 * ((xx >> 2) & 3);
    if (rot >= CIP) rot -= CIP;
    int cr = ci0 + rot;
    if (cr >= CIP) cr -= CIP;
    abase[s] = (y * ITX + xx) * CIP + cr;
  }

  __syncthreads();

  for (int mc = 0; mc < 4; ++mc) {
    f32x4 acc[2][3];
    #pragma unroll
    for (int mt = 0; mt < 2; ++mt)
      #pragma unroll
      for (int nt = 0; nt < 3; ++nt)
        acc[mt][nt] = f32x4{0.f, 0.f, 0.f, 0.f};

    #pragma unroll
    for (int s = 0; s < KSTEPS; ++s) {
      s16x8 bf0 = bpp[(s * 3 + 0) * 64];
      s16x8 bf1 = bpp[(s * 3 + 1) * 64];
      s16x8 bf2 = bpp[(s * 3 + 2) * 64];
      #pragma unroll
      for (int mt = 0; mt < 2; ++mt) {
        s16x8 a = *(const s16x8*)&in_lds[abase[s] + (mc * ITX + mt * 16) * CIP];
        acc[mt][0] = __builtin_amdgcn_mfma_f32_16x16x32_bf16(bf0, a, acc[mt][0], 0, 0, 0);
        acc[mt][1] = __builtin_amdgcn_mfma_f32_16x16x32_bf16(bf1, a, acc[mt][1], 0, 0, 0);
        acc[mt][2] = __builtin_amdgcn_mfma_f32_16x16x32_bf16(bf2, a, acc[mt][2], 0, 0, 0);
      }
    }

    if (BIGEPI) {
      // ---- single chunk: all 48 co, 2 barriers per mc ----
      __syncthreads();   // out_lds free
      #pragma unroll
      for (int nt = 0; nt < 3; ++nt) {
        #pragma unroll
        for (int mt = 0; mt < 2; ++mt) {
          #pragma unroll
          for (int r = 0; r < 4; ++r) {
            const int co_rel = nt * 16 + 4 * g + r;
            float iv = ((const float*)&inv4[nt])[r];
            float sv = ((const float*)&sh4[nt])[r];
            float val = fmaxf(acc[mt][nt][r] * iv + sv, 0.f);
            out_lds[(co_rel * 2 + py) * 64 + 2 * (mt * 16 + qx) + px] = val;
          }
        }
      }
      __syncthreads();   // out_lds filled
      // 48 co * 2 par * 16 float4 = 1536 -> 6 iters
      #pragma unroll
      for (int u = 0; u < 6; ++u) {
        int e = u * 256 + tid;
        int ow4 = e & 15, row = e >> 4;
        int co_l = row >> 1, ohp = row & 1;
        f32x4 vv = *(const f32x4*)&out_lds[row * 64 + 4 * ow4];
        long off = (((long)(n * outc + obase + co_l) * HOUT + 2 * (qY0 + mc) + ohp) * WOUT)
                   + 2 * qX0 + 4 * ow4;
        if (OBF16) {
          unsigned lo = (unsigned)f2bf(vv.x) | ((unsigned)f2bf(vv.y) << 16);
          unsigned hi = (unsigned)f2bf(vv.z) | ((unsigned)f2bf(vv.w) << 16);
          uint2 pk; pk.x = lo; pk.y = hi;
          *(uint2*)((u16*)outv + off) = pk;
        } else {
          __builtin_nontemporal_store(vv, (f32x4*)((float*)outv + off));
        }
      }
    } else {
      // ---- r8 path: two co-subchunks {nt 0,1}, {nt 2} ----
      #pragma unroll
      for (int sc = 0; sc < 2; ++sc) {
        const int ntlo = (sc == 0) ? 0 : 2;
        const int ntn  = (sc == 0) ? 2 : 1;
        const int coBase = ntlo * 16;
        __syncthreads();   // out_lds free
        #pragma unroll
        for (int ntl = 0; ntl < 2; ++ntl) {
          if (ntl < ntn) {
            const int nt = ntlo + ntl;
            #pragma unroll
            for (int mt = 0; mt < 2; ++mt) {
              #pragma unroll
              for (int r = 0; r < 4; ++r) {
                const int co_rel = ntl * 16 + 4 * g + r;
                float iv = ((const float*)&inv4[nt])[r];
                float sv = ((const float*)&sh4[nt])[r];
                float val = fmaxf(acc[mt][nt][r] * iv + sv, 0.f);
                out_lds[(co_rel * 2 + py) * 64 + 2 * (mt * 16 + qx) + px] = val;
              }
            }
          }
        }
        __syncthreads();   // out_lds filled
        const int nIter = ntn * 2;
        #pragma unroll
        for (int u = 0; u < 4; ++u) {
          if (u < nIter) {
            int e = u * 256 + tid;
            int ow4 = e & 15, row = e >> 4;
            int co_l = coBase + (row >> 1), ohp = row & 1;
            f32x4 vv = *(const f32x4*)&out_lds[row * 64 + 4 * ow4];
            long off = (((long)(n * outc + obase + co_l) * HOUT + 2 * (qY0 + mc) + ohp) * WOUT)
                       + 2 * qX0 + 4 * ow4;
            if (OBF16) {
              unsigned lo = (unsigned)f2bf(vv.x) | ((unsigned)f2bf(vv.y) << 16);
              unsigned hi = (unsigned)f2bf(vv.z) | ((unsigned)f2bf(vv.w) << 16);
              uint2 pk; pk.x = lo; pk.y = hi;
              *(uint2*)((u16*)outv + off) = pk;
            } else {
              __builtin_nontemporal_store(vv, (f32x4*)((float*)outv + off));
            }
          }
        }
      }
    }
  }
}

extern "C" void kernel_launch(void* const* d_in, const int* in_sizes, int n_in,
                              void* d_out, int out_size, void* d_ws, size_t ws_size,
                              hipStream_t stream) {
  const float* x    = (const float*)d_in[0];
  const float* w1   = (const float*)d_in[1];
  const float* b1   = (const float*)d_in[2];
  const float* g1   = (const float*)d_in[3];
  const float* be1  = (const float*)d_in[4];
  const float* m1   = (const float*)d_in[5];
  const float* v1   = (const float*)d_in[6];
  const float* w2a  = (const float*)d_in[7];
  const float* b2a  = (const float*)d_in[8];
  const float* g2a  = (const float*)d_in[9];
  const float* be2a = (const float*)d_in[10];
  const float* m2a  = (const float*)d_in[11];
  const float* v2a  = (const float*)d_in[12];
  const float* w2b  = (const float*)d_in[13];
  const float* b2b  = (const float*)d_in[14];
  const float* g2b  = (const float*)d_in[15];
  const float* be2b = (const float*)d_in[16];
  const float* m2b  = (const float*)d_in[17];
  const float* v2b  = (const float*)d_in[18];

  float* out = (float*)d_out;
  char* ws = (char*)d_ws;
  u16* xl1  = (u16*)ws;                         // 6291456 B
  u16* xl2  = (u16*)(ws + 6291456);             // 6291456 B
  u16* o2a  = (u16*)(ws + 12582912);            // 25165824 B
  u16* Bp1  = (u16*)(ws + 37748736);
  u16* Bp2a = (u16*)(ws + 37773312);
  u16* Bp2b = (u16*)(ws + 37847040);
  float* bnp1  = (float*)(ws + 37920768);
  float* bnp2a = (float*)(ws + 37921152);
  float* bnp2b = (float*)(ws + 37921536);

  // fused: dwt l1+l2 (768 blocks) + 3x setup (432 blocks)
  prep_kernel<<<1200, 256, 0, stream>>>(
      x, xl1, xl2,
      w1, b1, g1, be1, m1, v1, Bp1, bnp1,
      w2a, b2a, g2a, be2a, m2a, v2a, Bp2a, bnp2a,
      w2b, b2b, g2b, be2b, m2b, v2b, Bp2b, bnp2b);

  // conv2a: (16,48,64,64) -> o2a (bf16)           [r8 path]
  convt_mfma<48, 48, 64, 64, true, false><<<dim3(2, 16, 16), 256, 0, stream>>>(
      xl2, Bp2a, bnp2a, o2a, 48, 0);
  // conv1: (16,12,128,128) -> out ch 0..47 (fp32) [BIGEPI: 8 barriers]
  convt_mfma<12, 16, 128, 128, false, true><<<dim3(4, 32, 16), 256, 0, stream>>>(
      xl1, Bp1, bnp1, out, 96, 0);
  // conv2b: (16,48,128,128) -> out ch 48..95 (fp32) [r8 path]
  convt_mfma<48, 48, 128, 128, false, false><<<dim3(4, 32, 16), 256, 0, stream>>>(
      o2a, Bp2b, bnp2b, out, 96, 48);
}